// Round 1
// baseline (96.290 us; speedup 1.0000x reference)
//
#include <hip/hip_runtime.h>

// Problem constants (match reference)
#define BB 64
#define N_WAY 5
#define N_SHOT 5
#define QUERY 15
#define NUM_SLOT 8
#define DD 640
#define IMGS (N_WAY * QUERY)      // 75
#define NS (BB * N_WAY * N_SHOT)  // 1600 support rows
#define NQROWS (BB * IMGS)        // 4800 query rows
#define ROWSZ (NUM_SLOT * DD)     // 5120 floats per row
#define NELEM (BB * IMGS)         // 4800 (loss elements)

// ---------------- K1: support slot-means: mean over (shot, d) ----------------
// slotmean_sup[row*8+slot] = mean_{shot,d} out_f[((row*5+shot)*8+slot)*640+d] / (5*640)
__global__ void k_sup_slotmean(const float* __restrict__ out_f,
                               float* __restrict__ slotmean_sup) {
    int bid = blockIdx.x;            // row*8 + slot, row in [0, 320)
    int row = bid >> 3, slot = bid & 7;
    int tid = threadIdx.x;           // 64
    float s = 0.f;
    for (int d = tid; d < DD; d += 64) {
        #pragma unroll
        for (int sh = 0; sh < N_SHOT; ++sh)
            s += out_f[((size_t)(row * N_SHOT + sh) * NUM_SLOT + slot) * DD + d];
    }
    #pragma unroll
    for (int off = 32; off; off >>= 1) s += __shfl_down(s, off, 64);
    if (tid == 0) slotmean_sup[bid] = s / (float)(N_SHOT * DD);
}

// ---------------- K2: greedy cover-select ----------------
__global__ void k_cover(const float* __restrict__ slotmean_sup,
                        int* __restrict__ max_s) {
    int j = threadIdx.x;             // 64 threads, one per batch
    if (j >= BB) return;
    unsigned taken = 0u;
    for (int c = 0; c < N_WAY; ++c) {
        const float* rowp = slotmean_sup + (j * N_WAY + c) * NUM_SLOT;
        float best = -3.0e38f; int bi = 0;
        #pragma unroll
        for (int s = 0; s < NUM_SLOT; ++s) {
            if (!(taken & (1u << s))) {
                float v = rowp[s];
                if (v > best) { best = v; bi = s; }   // strict > = first-occurrence argmax
            }
        }
        taken |= (1u << bi);
        max_s[j * N_WAY + c] = bi;
    }
}

// ---------------- K3: prototypes (shot-mean of selected slot) ----------------
__global__ void k_proto(const float* __restrict__ out_f,
                        const int* __restrict__ max_s,
                        float* __restrict__ proto) {
    int row = blockIdx.x;            // j*5+c, in [0,320)
    int ms = max_s[row];
    int tid = threadIdx.x;           // 128
    for (int d = tid; d < DD; d += 128) {
        float s = 0.f;
        #pragma unroll
        for (int sh = 0; sh < N_SHOT; ++sh)
            s += out_f[((size_t)(row * N_SHOT + sh) * NUM_SLOT + ms) * DD + d];
        proto[row * DD + d] = s / (float)N_SHOT;
    }
}

// ---------------- K4: query slot-means ----------------
__global__ void k_qslotmean(const float* __restrict__ out_f,
                            float* __restrict__ qslotmean) {
    int bid = blockIdx.x;            // r*8 + slot, r in [0,4800)
    int r = bid >> 3, slot = bid & 7;
    const float* p = out_f + (size_t)(NS + r) * ROWSZ + slot * DD;
    int tid = threadIdx.x;           // 64
    float s = 0.f;
    for (int d = tid; d < DD; d += 64) s += p[d];
    #pragma unroll
    for (int off = 32; off; off >>= 1) s += __shfl_down(s, off, 64);
    if (tid == 0) qslotmean[bid] = s / (float)DD;
}

// ---------------- K5: prefix running argmax (k indices) ----------------
__global__ void k_runmax(const float* __restrict__ qslotmean,
                         const int* __restrict__ max_s,
                         int* __restrict__ k_idx) {
    int j = threadIdx.x;             // 64 threads, one per batch
    if (j >= BB) return;
    int ms[N_WAY];
    #pragma unroll
    for (int c = 0; c < N_WAY; ++c) ms[c] = max_s[j * N_WAY + c];
    float best = -3.0e38f; int bi = 0;
    for (int s = 0; s < IMGS; ++s) {
        #pragma unroll
        for (int c = 0; c < N_WAY; ++c) {
            float v = qslotmean[(j * IMGS + s) * NUM_SLOT + ms[c]];
            if (v > best) { best = v; bi = s * N_WAY + c; }  // ascending l, strict >
        }
        k_idx[j * IMGS + s] = bi;
    }
}

// ---------------- K6: distances + log-softmax + per-element loss/acc ----------------
// part layout: part[0][e]=nll1, part[1][e]=nll2, part[2][e]=acc1, part[3][e]=acc2
__global__ void k_loss(const float* __restrict__ out_f,
                       const float* __restrict__ proto,
                       const int* __restrict__ max_s,
                       const int* __restrict__ k_idx,
                       const int* __restrict__ labels_query,
                       float* __restrict__ part) {
    int bid = blockIdx.x;            // j*75 + m
    int j = bid / IMGS, m = bid % IMGS;
    int tid = threadIdx.x;           // 64

    int ms1 = max_s[j * N_WAY + m / QUERY];
    const float* q1 = out_f + (size_t)(NS + j * IMGS + m) * ROWSZ + ms1 * DD;

    int kk = k_idx[bid];
    int s2 = kk / N_WAY, c2k = kk % N_WAY;
    int ms2 = max_s[j * N_WAY + c2k];
    const float* q2 = out_f + (size_t)(NS + j * IMGS + s2) * ROWSZ + ms2 * DD;

    const float* pr = proto + j * N_WAY * DD;

    float d1[N_WAY] = {0, 0, 0, 0, 0};
    float d2[N_WAY] = {0, 0, 0, 0, 0};
    for (int d = tid; d < DD; d += 64) {
        float a = q1[d];
        float b = q2[d];
        #pragma unroll
        for (int n = 0; n < N_WAY; ++n) {
            float p = pr[n * DD + d];
            float t1 = a - p; d1[n] = fmaf(t1, t1, d1[n]);
            float t2 = b - p; d2[n] = fmaf(t2, t2, d2[n]);
        }
    }
    #pragma unroll
    for (int n = 0; n < N_WAY; ++n) {
        #pragma unroll
        for (int off = 32; off; off >>= 1) {
            d1[n] += __shfl_down(d1[n], off, 64);
            d2[n] += __shfl_down(d2[n], off, 64);
        }
    }
    if (tid == 0) {
        int label = labels_query[bid];   // flat [B,QUERY,N_WAY,1] index == j*75+m
        // path 1
        {
            float li[N_WAY];
            float mx = -3.0e38f;
            #pragma unroll
            for (int n = 0; n < N_WAY; ++n) { li[n] = -d1[n]; mx = fmaxf(mx, li[n]); }
            float se = 0.f;
            #pragma unroll
            for (int n = 0; n < N_WAY; ++n) se += expf(li[n] - mx);
            float lse = mx + logf(se);
            int bi = 0; float bv = li[0];
            #pragma unroll
            for (int n = 1; n < N_WAY; ++n) if (li[n] > bv) { bv = li[n]; bi = n; }
            part[0 * NELEM + bid] = -(li[label] - lse);
            part[2 * NELEM + bid] = (bi == label) ? 1.f : 0.f;
        }
        // path 2
        {
            float li[N_WAY];
            float mx = -3.0e38f;
            #pragma unroll
            for (int n = 0; n < N_WAY; ++n) { li[n] = -d2[n]; mx = fmaxf(mx, li[n]); }
            float se = 0.f;
            #pragma unroll
            for (int n = 0; n < N_WAY; ++n) se += expf(li[n] - mx);
            float lse = mx + logf(se);
            int bi = 0; float bv = li[0];
            #pragma unroll
            for (int n = 1; n < N_WAY; ++n) if (li[n] > bv) { bv = li[n]; bi = n; }
            part[1 * NELEM + bid] = -(li[label] - lse);
            part[3 * NELEM + bid] = (bi == label) ? 1.f : 0.f;
        }
    }
}

// ---------------- K7: final deterministic tree reduction ----------------
__global__ void k_final(const float* __restrict__ part,
                        const float* __restrict__ att_loss,
                        float* __restrict__ out) {
    __shared__ float red[256];
    int t = threadIdx.x;             // 256
    for (int c = 0; c < 4; ++c) {
        float s = 0.f;
        for (int i = t; i < NELEM; i += 256) s += part[c * NELEM + i];
        red[t] = s;
        __syncthreads();
        for (int w = 128; w; w >>= 1) {
            if (t < w) red[t] += red[t + w];
            __syncthreads();
        }
        if (t == 0) {
            float v = red[0] / (float)NELEM;
            if (c == 0) v += 0.1f * att_loss[0];
            out[c] = v;
        }
        __syncthreads();
    }
}

extern "C" void kernel_launch(void* const* d_in, const int* in_sizes, int n_in,
                              void* d_out, int out_size, void* d_ws, size_t ws_size,
                              hipStream_t stream) {
    const float* out_f        = (const float*)d_in[0];
    // d_in[1] = labels_support (unused by the reference's train path)
    const int*   labels_query = (const int*)d_in[2];
    const float* att_loss     = (const float*)d_in[3];
    float* out = (float*)d_out;

    // workspace layout (floats, then ints)
    float* slotmean_sup = (float*)d_ws;                       // 2560 f
    float* qslotmean    = slotmean_sup + 2560;                // 38400 f
    float* proto        = qslotmean + 38400;                  // 204800 f
    float* part         = proto + 204800;                     // 4*4800 = 19200 f
    int*   max_s        = (int*)(part + 19200);               // 320 i
    int*   k_idx        = max_s + 320;                        // 4800 i
    // total ≈ 1.03 MB

    k_sup_slotmean<<<320 * NUM_SLOT, 64, 0, stream>>>(out_f, slotmean_sup);
    k_cover<<<1, 64, 0, stream>>>(slotmean_sup, max_s);
    k_proto<<<320, 128, 0, stream>>>(out_f, max_s, proto);
    k_qslotmean<<<NQROWS * NUM_SLOT, 64, 0, stream>>>(out_f, qslotmean);
    k_runmax<<<1, 64, 0, stream>>>(qslotmean, max_s, k_idx);
    k_loss<<<NELEM, 64, 0, stream>>>(out_f, proto, max_s, k_idx, labels_query, part);
    k_final<<<1, 256, 0, stream>>>(part, att_loss, out);
}

// Round 2
// 76.884 us; speedup vs baseline: 1.2524x; 1.2524x over previous
//
#include <hip/hip_runtime.h>

// Problem constants (match reference)
#define BB 64
#define N_WAY 5
#define N_SHOT 5
#define QUERY 15
#define NUM_SLOT 8
#define DD 640
#define IMGS (N_WAY * QUERY)      // 75
#define NS (BB * N_WAY * N_SHOT)  // 1600 support rows
#define NROWS 6400                // total rows
#define NQROWS (BB * IMGS)        // 4800 query rows
#define ROWSZ (NUM_SLOT * DD)     // 5120 floats per row
#define F4_PER_SLOT 160           // 640/4
#define NELEM (BB * IMGS)         // 4800 loss elements

// ---------------- K_A: per-row slot means over d, ALL 6400 rows ----------------
// One block per row; 256 threads = 8 slot-groups of 32 lanes; float4 loads.
// rowmean[r*8+slot] = mean_d out_f[r, slot, :]
__global__ __launch_bounds__(256) void k_rowmean(const float* __restrict__ out_f,
                                                 float* __restrict__ rowmean) {
    int r = blockIdx.x;               // 0..6399
    int t = threadIdx.x;              // 256
    int slot = t >> 5;                // 0..7
    int l = t & 31;
    const float4* p = (const float4*)(out_f + (size_t)r * ROWSZ) + slot * F4_PER_SLOT;
    float s = 0.f;
    #pragma unroll
    for (int k = 0; k < 5; ++k) {     // 160 f4 over 32 lanes
        float4 v = p[l + k * 32];
        s += (v.x + v.y) + (v.z + v.w);
    }
    #pragma unroll
    for (int off = 16; off; off >>= 1) s += __shfl_down(s, off, 32);
    if (l == 0) rowmean[r * NUM_SLOT + slot] = s * (1.f / DD);
}

// ---------------- K_B: cover-select + prefix running argmax (serial, per batch) ----
__global__ void k_select(const float* __restrict__ rowmean,
                         int* __restrict__ max_s,
                         int* __restrict__ k_idx) {
    int j = threadIdx.x;              // 64 threads, one per batch
    if (j >= BB) return;

    // support slot means: mean over shots of per-row means (== mean over shot,d)
    float supm[N_WAY][NUM_SLOT];
    const float* sb = rowmean + (size_t)j * (N_WAY * N_SHOT) * NUM_SLOT;
    #pragma unroll
    for (int c = 0; c < N_WAY; ++c)
        #pragma unroll
        for (int s = 0; s < NUM_SLOT; ++s) {
            float a = 0.f;
            #pragma unroll
            for (int sh = 0; sh < N_SHOT; ++sh)
                a += sb[(c * N_SHOT + sh) * NUM_SLOT + s];
            supm[c][s] = a * 0.2f;
        }

    // greedy cover select (first-occurrence argmax among untaken slots)
    int ms[N_WAY];
    unsigned taken = 0u;
    #pragma unroll
    for (int c = 0; c < N_WAY; ++c) {
        float best = -3.0e38f; int bi = 0;
        #pragma unroll
        for (int s = 0; s < NUM_SLOT; ++s)
            if (!(taken & (1u << s)) && supm[c][s] > best) { best = supm[c][s]; bi = s; }
        taken |= (1u << bi);
        ms[c] = bi;
        max_s[j * N_WAY + c] = bi;
    }

    // prefix running argmax over cand means (flat order (s, c), first occurrence)
    const float* qb = rowmean + (size_t)(NS + j * IMGS) * NUM_SLOT;
    float best = -3.0e38f; int bi = 0;
    for (int s = 0; s < IMGS; ++s) {
        #pragma unroll
        for (int c = 0; c < N_WAY; ++c) {
            float v = qb[s * NUM_SLOT + ms[c]];
            if (v > best) { best = v; bi = s * N_WAY + c; }
        }
        k_idx[j * IMGS + s] = bi;
    }
}

// ---------------- K_C: prototypes (shot-mean of selected slot) + ||p||^2 ----------
__global__ __launch_bounds__(64) void k_proto(const float* __restrict__ out_f,
                                              const int* __restrict__ max_s,
                                              float* __restrict__ proto,
                                              float* __restrict__ pn2) {
    int row = blockIdx.x;             // j*5+c, 0..319
    int ms = max_s[row];
    int t = threadIdx.x;              // 64
    float ssq = 0.f;
    for (int i = t; i < F4_PER_SLOT; i += 64) {
        float4 a = make_float4(0.f, 0.f, 0.f, 0.f);
        #pragma unroll
        for (int sh = 0; sh < N_SHOT; ++sh) {
            const float4* p = (const float4*)(out_f +
                ((size_t)(row * N_SHOT + sh) * NUM_SLOT + ms) * DD);
            float4 v = p[i];
            a.x += v.x; a.y += v.y; a.z += v.z; a.w += v.w;
        }
        a.x *= 0.2f; a.y *= 0.2f; a.z *= 0.2f; a.w *= 0.2f;
        ((float4*)(proto + (size_t)row * DD))[i] = a;
        ssq += a.x * a.x + a.y * a.y + a.z * a.z + a.w * a.w;
    }
    #pragma unroll
    for (int off = 32; off; off >>= 1) ssq += __shfl_down(ssq, off, 64);
    if (t == 0) pn2[row] = ssq;
}

// ---------------- K_D: dot-product scores + log-softmax + per-element loss/acc ----
// score_n = 2 q.p_n - ||p_n||^2  (the ||q||^2 term cancels in log_softmax/argmax)
__global__ __launch_bounds__(64) void k_loss(const float* __restrict__ out_f,
                                             const float* __restrict__ proto,
                                             const float* __restrict__ pn2,
                                             const int* __restrict__ max_s,
                                             const int* __restrict__ k_idx,
                                             const int* __restrict__ labels_query,
                                             float* __restrict__ part) {
    int bid = blockIdx.x;             // j*75 + m
    int j = bid / IMGS, m = bid % IMGS;
    int t = threadIdx.x;              // 64

    int ms1 = max_s[j * N_WAY + m / QUERY];
    const float4* q1 = (const float4*)(out_f +
        (size_t)(NS + j * IMGS + m) * ROWSZ + ms1 * DD);

    int kk = k_idx[bid];
    int s2 = kk / N_WAY, c2 = kk % N_WAY;
    int ms2 = max_s[j * N_WAY + c2];
    const float4* q2 = (const float4*)(out_f +
        (size_t)(NS + j * IMGS + s2) * ROWSZ + ms2 * DD);

    const float4* pr = (const float4*)(proto + (size_t)j * N_WAY * DD);

    float s1[N_WAY] = {0, 0, 0, 0, 0};
    float s2a[N_WAY] = {0, 0, 0, 0, 0};
    for (int i = t; i < F4_PER_SLOT; i += 64) {
        float4 a = q1[i];
        float4 b = q2[i];
        #pragma unroll
        for (int n = 0; n < N_WAY; ++n) {
            float4 p = pr[n * F4_PER_SLOT + i];
            s1[n]  += a.x * p.x + a.y * p.y + a.z * p.z + a.w * p.w;
            s2a[n] += b.x * p.x + b.y * p.y + b.z * p.z + b.w * p.w;
        }
    }
    #pragma unroll
    for (int n = 0; n < N_WAY; ++n) {
        #pragma unroll
        for (int off = 32; off; off >>= 1) {
            s1[n]  += __shfl_down(s1[n],  off, 64);
            s2a[n] += __shfl_down(s2a[n], off, 64);
        }
    }
    if (t == 0) {
        int label = labels_query[bid];
        const float* p2 = pn2 + j * N_WAY;
        // path 1
        {
            float li[N_WAY]; float mx = -3.0e38f;
            #pragma unroll
            for (int n = 0; n < N_WAY; ++n) { li[n] = 2.f * s1[n] - p2[n]; mx = fmaxf(mx, li[n]); }
            float se = 0.f;
            #pragma unroll
            for (int n = 0; n < N_WAY; ++n) se += expf(li[n] - mx);
            float lse = mx + logf(se);
            int bi = 0; float bv = li[0];
            #pragma unroll
            for (int n = 1; n < N_WAY; ++n) if (li[n] > bv) { bv = li[n]; bi = n; }
            part[0 * NELEM + bid] = -(li[label] - lse);
            part[2 * NELEM + bid] = (bi == label) ? 1.f : 0.f;
        }
        // path 2
        {
            float li[N_WAY]; float mx = -3.0e38f;
            #pragma unroll
            for (int n = 0; n < N_WAY; ++n) { li[n] = 2.f * s2a[n] - p2[n]; mx = fmaxf(mx, li[n]); }
            float se = 0.f;
            #pragma unroll
            for (int n = 0; n < N_WAY; ++n) se += expf(li[n] - mx);
            float lse = mx + logf(se);
            int bi = 0; float bv = li[0];
            #pragma unroll
            for (int n = 1; n < N_WAY; ++n) if (li[n] > bv) { bv = li[n]; bi = n; }
            part[1 * NELEM + bid] = -(li[label] - lse);
            part[3 * NELEM + bid] = (bi == label) ? 1.f : 0.f;
        }
    }
}

// ---------------- K_E: final deterministic tree reduction ----------------
__global__ void k_final(const float* __restrict__ part,
                        const float* __restrict__ att_loss,
                        float* __restrict__ out) {
    __shared__ float red[256];
    int t = threadIdx.x;              // 256
    for (int c = 0; c < 4; ++c) {
        float s = 0.f;
        for (int i = t; i < NELEM; i += 256) s += part[c * NELEM + i];
        red[t] = s;
        __syncthreads();
        for (int w = 128; w; w >>= 1) {
            if (t < w) red[t] += red[t + w];
            __syncthreads();
        }
        if (t == 0) {
            float v = red[0] / (float)NELEM;
            if (c == 0) v += 0.1f * att_loss[0];
            out[c] = v;
        }
        __syncthreads();
    }
}

extern "C" void kernel_launch(void* const* d_in, const int* in_sizes, int n_in,
                              void* d_out, int out_size, void* d_ws, size_t ws_size,
                              hipStream_t stream) {
    const float* out_f        = (const float*)d_in[0];
    // d_in[1] = labels_support (unused by the reference's train path)
    const int*   labels_query = (const int*)d_in[2];
    const float* att_loss     = (const float*)d_in[3];
    float* out = (float*)d_out;

    // workspace layout
    float* rowmean = (float*)d_ws;                 // 6400*8 = 51200 f
    float* proto   = rowmean + NROWS * NUM_SLOT;   // 204800 f
    float* pn2     = proto + 320 * DD;             // 320 f
    float* part    = pn2 + 320;                    // 4*4800 f
    int*   max_s   = (int*)(part + 4 * NELEM);     // 320 i
    int*   k_idx   = max_s + 320;                  // 4800 i

    k_rowmean<<<NROWS, 256, 0, stream>>>(out_f, rowmean);
    k_select<<<1, 64, 0, stream>>>(rowmean, max_s, k_idx);
    k_proto<<<320, 64, 0, stream>>>(out_f, max_s, proto, pn2);
    k_loss<<<NELEM, 64, 0, stream>>>(out_f, proto, pn2, max_s, k_idx, labels_query, part);
    k_final<<<1, 256, 0, stream>>>(part, att_loss, out);
}